// Round 5
// baseline (662.390 us; speedup 1.0000x reference)
//
#include <hip/hip_runtime.h>

#define NBINS 20
#define C 128
#define BLOCKS 2048

// clang-native vector type: required by __builtin_nontemporal_load.
typedef float vf4 __attribute__((ext_vector_type(4)));

// ws layout: float bcsum[BLOCKS][NBINS] | unsigned bcc[BLOCKS][NBINS] (320 KB).
// Every block writes all 20 slots unconditionally -> no ws zeroing needed.
// NOTE: the harness's 2 GB ws re-poison fill (~318 us at write roofline) is a
// fixed floor we don't control.

// pass1, round-5 single-variable change vs round 4: 32 lanes/row so every
// global_load_dwordx4 covers 2 consecutive rows = 1 KB CONTIGUOUS per
// instruction (the fill kernel's pattern, 6.4 TB/s), instead of 8x128 B
// segments at 512 B stride. Macro pattern unchanged: block-contiguous spans,
// 8-row double-buffered steps, nt loads, private (non-atomic) writeout.
__global__ __launch_bounds__(256) void ece_pass1(
    const float* __restrict__ sm, const int* __restrict__ labels, int N,
    float* __restrict__ bcsum, unsigned* __restrict__ bcc) {
  __shared__ float s_csum[NBINS];
  __shared__ unsigned s_cc[NBINS];  // cnt in [15:0] | cor in [31:16]
  const int tid = threadIdx.x;
  if (tid < NBINS) { s_csum[tid] = 0.f; s_cc[tid] = 0u; }
  __syncthreads();

  const int lane = tid & 63;
  const int q = lane & 31;   // column quarter: cols [q*4, q*4+4)
  const int g = lane >> 5;   // row parity within an instruction (2 rows/instr)
  const int w = tid >> 6;    // wave id in block

  const long long rpb = ((long long)N + BLOCKS - 1) / BLOCKS;  // rows/block
  const long long lo  = (long long)blockIdx.x * rpb;
  const long long hi  = min(lo + rpb, (long long)N);

  vf4 va[4], vb[4];
  int la = 0, lb = 0;

  // Issue the 8-row step at base rb: 4 loads, instr k covers rows rb+2k,
  // rb+2k+1 -> 64 lanes span 1 KB contiguous. Plus one label dword per lane
  // (lanes 0..7 carry the step's 8 labels; 8x duplicated across the wave).
  auto issue = [&](long long rb, vf4 (&v)[4], int& lab) {
#pragma unroll
    for (int k = 0; k < 4; ++k) {
      const long long row = rb + 2 * k + g;
      if (row < hi)
        v[k] = __builtin_nontemporal_load((const vf4*)(sm + row * (long long)C) + q);
      else
        v[k] = (vf4){-2.f, -2.f, -2.f, -2.f};
    }
    const long long lrow = rb + (lane & 7);
    lab = (lrow < hi) ? labels[lrow] : -1;
  };

  // Per instruction k: in-lane argmax over 4 values (ascending col -> first
  // occurrence), 5-round xor-shfl reduce within each 32-lane group (explicit
  // (value, col) tie-break preserves jnp.argmax first-max semantics), then
  // group leader (lane&31)==0 does 2 LDS atomics.
  auto process = [&](long long rb, const vf4 (&v)[4], int lab) {
#pragma unroll
    for (int k = 0; k < 4; ++k) {
      const vf4 p = v[k];
      const int c0 = q * 4;
      float bv = p.x; int bi = c0;
      if (p.y > bv) { bv = p.y; bi = c0 + 1; }
      if (p.z > bv) { bv = p.z; bi = c0 + 2; }
      if (p.w > bv) { bv = p.w; bi = c0 + 3; }
#pragma unroll
      for (int off = 1; off <= 16; off <<= 1) {
        const float ov = __shfl_xor(bv, off);
        const int   oi = __shfl_xor(bi, off);
        if (ov > bv || (ov == bv && oi < bi)) { bv = ov; bi = oi; }
      }
      const int lk = __shfl(lab, 2 * k + g);  // label of this group's row
      const long long row = rb + 2 * k + g;
      if (q == 0 && row < hi) {
        int bin = (int)ceilf(bv * 20.0f) - 1;  // matches jnp.ceil(conf*20)-1
        bin = min(max(bin, 0), NBINS - 1);
        atomicAdd(&s_csum[bin], bv);
        // per-block rows <= 512 << 2^16 -> packed add is safe
        atomicAdd(&s_cc[bin], 1u + ((bi == lk) ? 0x10000u : 0u));
      }
    }
  };

  // Waves interleave at 8-row granularity within the block's contiguous span
  // (block window = 32 rows = 16 KB contiguous), register double-buffered.
  long long rb = lo + (long long)w * 8;
  if (rb < hi) {
    issue(rb, va, la);
    while (true) {
      long long rn = rb + 32;
      if (rn < hi) issue(rn, vb, lb);  // prefetch across process() tail
      process(rb, va, la);
      rb = rn;
      if (rb >= hi) break;
      rn = rb + 32;
      if (rn < hi) issue(rn, va, la);
      process(rb, vb, lb);
      rb = rn;
      if (rb >= hi) break;
    }
  }

  __syncthreads();
  if (tid < NBINS) {  // non-atomic private-slot writeout (zeros included)
    bcsum[blockIdx.x * NBINS + tid] = s_csum[tid];
    bcc[blockIdx.x * NBINS + tid]   = s_cc[tid];
  }
}

// pass2: reduce 2048 per-block partials (320 KB, L2-resident).
// 640 threads: thread t -> bin t%20, chunk t/20 (32 chunks of 64 blocks).
__global__ void ece_pass2(const float* __restrict__ bcsum,
                          const unsigned* __restrict__ bcc,
                          float* __restrict__ out, int N) {
  __shared__ double  sc[32][NBINS];
  __shared__ unsigned scnt[32][NBINS];
  __shared__ unsigned scor[32][NBINS];
  const int t = threadIdx.x;
  const int bin = t % NBINS;
  const int chunk = t / NBINS;  // 0..31
  double cs = 0.0;
  unsigned cn = 0, co = 0;
  for (int b = chunk; b < BLOCKS; b += 32) {
    cs += (double)bcsum[b * NBINS + bin];
    const unsigned cc = bcc[b * NBINS + bin];
    cn += cc & 0xFFFFu;
    co += cc >> 16;
  }
  sc[chunk][bin] = cs;
  scnt[chunk][bin] = cn;
  scor[chunk][bin] = co;
  __syncthreads();

  double contrib = 0.0;
  if (t < NBINS) {
    double csum = 0.0;
    unsigned cnt = 0, cor = 0;
#pragma unroll
    for (int gch = 0; gch < 32; ++gch) {
      csum += sc[gch][t];
      cnt += scnt[gch][t];
      cor += scor[gch][t];
    }
    const double safe = cnt ? (double)cnt : 1.0;
    const double avg_conf = csum / safe;
    const double avg_acc  = (double)cor / safe;
    out[1 + t] = cnt ? (float)avg_acc : 0.f;  // ys
    if (cnt) contrib = fabs(avg_conf - avg_acc) * ((double)cnt / (double)N);
  }
#pragma unroll
  for (int off = 16; off >= 1; off >>= 1) contrib += __shfl_down(contrib, off);
  if (t == 0) out[0] = (float)contrib;  // ece
}

extern "C" void kernel_launch(void* const* d_in, const int* in_sizes, int n_in,
                              void* d_out, int out_size, void* d_ws, size_t ws_size,
                              hipStream_t stream) {
  const float* sm     = (const float*)d_in[0];
  const int*   labels = (const int*)d_in[1];
  const int N = in_sizes[1];  // labels count = number of rows

  float*    bcsum = (float*)d_ws;
  unsigned* bcc   = (unsigned*)((char*)d_ws + BLOCKS * NBINS * sizeof(float));

  // No ws memset needed: every bcsum/bcc slot is written unconditionally.
  ece_pass1<<<BLOCKS, 256, 0, stream>>>(sm, labels, N, bcsum, bcc);
  ece_pass2<<<1, 640, 0, stream>>>(bcsum, bcc, (float*)d_out, N);
}